// Round 2
// baseline (306.099 us; speedup 1.0000x reference)
//
#include <hip/hip_runtime.h>
#include <cmath>

#define BINS 10
#define EDGE_TOP (1.0f + 1e-6f)
#define NCOPY 64          // one histogram copy per lane -> no intra-wave same-address atomics
#define SLOT 11           // stride coprime with 32 banks -> <=2-way bank aliasing
#define BLK 256
#define GRID 2000

// Classify one element: bin index (clipped to [0,9]) and g value.
// Near-bin-boundary values recomputed with double-precision exp so the
// fp32-rounded result matches numpy's fp32 exp (proven: absmax 7.8e-3 in R1).
__device__ __forceinline__ void ghm_classify(float p, int& bin, float& g_out) {
    float ef  = expf(-p);
    float g   = fabsf(ef - 1.0f);
    float g10 = g * 10.0f;
    int   b   = (int)g10;          // g >= 0, trunc == floor
    float fb  = (float)b;
    bool hazard = (g10 - fb < 1e-4f) || (fb + 1.0f - g10 < 1e-4f) ||
                  (fabsf(g - EDGE_TOP) < 4e-6f);
    if (hazard) {
        double ed = exp(-(double)p);
        float ef2 = (float)ed;     // ~correctly-rounded fp32 exp
        g   = fabsf(ef2 - 1.0f);
        g10 = g * 10.0f;
        b   = (int)g10;
    }
    bin   = (b < 9) ? b : 9;
    g_out = g;
}

// Pass 1: per-bin counts of in-bin valid samples + total valid count.
// Histogram: 64 lane-private LDS copies (stride 11) via ds atomics;
// valid count in registers + wave shuffle reduce.
__global__ __launch_bounds__(BLK) void ghm_hist(
    const float* __restrict__ pred, const float* __restrict__ lw,
    unsigned int* __restrict__ cnt, int n)
{
    __shared__ unsigned int lh[NCOPY * SLOT];
    for (int j = threadIdx.x; j < NCOPY * SLOT; j += BLK) lh[j] = 0u;
    __syncthreads();

    const int lane = threadIdx.x & 63;
    const unsigned int hbase = (unsigned int)lane * SLOT;
    unsigned int vcnt = 0;

    const int tid = blockIdx.x * BLK + threadIdx.x;
    const int S   = gridDim.x * BLK;
    const int n4  = n >> 2;
    const float4* p4 = (const float4*)pred;
    const float4* w4 = (const float4*)lw;

    int i = tid;
    // main loop: 4 float4s of pred + 4 of lw issued back-to-back (8 loads in flight)
    for (; i + 3 * S < n4; i += 4 * S) {
        float4 P0 = p4[i];         float4 P1 = p4[i + S];
        float4 P2 = p4[i + 2 * S]; float4 P3 = p4[i + 3 * S];
        float4 W0 = w4[i];         float4 W1 = w4[i + S];
        float4 W2 = w4[i + 2 * S]; float4 W3 = w4[i + 3 * S];
        float ps[16] = {P0.x,P0.y,P0.z,P0.w, P1.x,P1.y,P1.z,P1.w,
                        P2.x,P2.y,P2.z,P2.w, P3.x,P3.y,P3.z,P3.w};
        float ws[16] = {W0.x,W0.y,W0.z,W0.w, W1.x,W1.y,W1.z,W1.w,
                        W2.x,W2.y,W2.z,W2.w, W3.x,W3.y,W3.z,W3.w};
#pragma unroll
        for (int k = 0; k < 16; ++k) {
            bool valid = ws[k] > 0.0f;
            vcnt += valid ? 1u : 0u;
            int bin; float g;
            ghm_classify(ps[k], bin, g);
            if (valid && g < EDGE_TOP)
                atomicAdd(&lh[hbase + bin], 1u);
        }
    }
    for (; i < n4; i += S) {
        float4 P = p4[i];
        float4 W = w4[i];
        float ps[4] = {P.x, P.y, P.z, P.w};
        float ws[4] = {W.x, W.y, W.z, W.w};
#pragma unroll
        for (int k = 0; k < 4; ++k) {
            bool valid = ws[k] > 0.0f;
            vcnt += valid ? 1u : 0u;
            int bin; float g;
            ghm_classify(ps[k], bin, g);
            if (valid && g < EDGE_TOP)
                atomicAdd(&lh[hbase + bin], 1u);
        }
    }
    // scalar tail (n % 4), one thread (empty for this shape)
    if (tid == 0) {
        for (int j = n4 << 2; j < n; ++j) {
            bool valid = lw[j] > 0.0f;
            vcnt += valid ? 1u : 0u;
            int bin; float g;
            ghm_classify(pred[j], bin, g);
            if (valid && g < EDGE_TOP)
                atomicAdd(&lh[hbase + bin], 1u);
        }
    }

    // valid count: wave shuffle reduce -> one global atomic per wave
#pragma unroll
    for (int off = 32; off > 0; off >>= 1)
        vcnt += __shfl_down(vcnt, off, 64);
    if (lane == 0) atomicAdd(&cnt[BINS], vcnt);

    // bin counts: sum the 64 copies -> one global atomic per bin per block
    __syncthreads();
    if (threadIdx.x < BINS) {
        unsigned int s = 0;
        for (int c = 0; c < NCOPY; ++c) s += lh[c * SLOT + threadIdx.x];
        atomicAdd(&cnt[threadIdx.x], s);
    }
}

// Pass 2: out = in_bin ? w[bin] * pred : 0.
// Each wave finalizes the 10 bin weights itself (no separate dispatch):
// lane l<10 holds w[l]; sentinel index 15 -> lane 15 -> weight 0.
// Per-element lookup = one ds_bpermute.
__global__ __launch_bounds__(BLK) void ghm_apply(
    const float* __restrict__ pred, const float* __restrict__ lw,
    const unsigned int* __restrict__ cnt, float* __restrict__ out, int n)
{
    const int lane = threadIdx.x & 63;

    // wave-cooperative finalize, fp32 op order matches reference:
    // w = (tot / counts[b]) / n_nonempty  for nonempty bins, else 0.
    unsigned int cv = cnt[lane < 10 ? lane : 10];
    float totf = fmaxf((float)__shfl(cv, 10, 64), 1.0f);
    unsigned long long nem = __ballot(lane < 10 && cv > 0u);
    int nne = __popcll(nem);
    float nf = fmaxf((float)nne, 1.0f);
    float wfl = 0.0f;
    if (lane < 10 && cv > 0u) {
        wfl = totf / (float)cv;
        if (nne > 0) wfl = wfl / nf;
    }
    const int wfi = __float_as_int(wfl);

    const int tid = blockIdx.x * BLK + threadIdx.x;
    const int S   = gridDim.x * BLK;
    const int n4  = n >> 2;
    const float4* p4 = (const float4*)pred;
    const float4* w4 = (const float4*)lw;
    float4* o4       = (float4*)out;

    int i = tid;
    for (; i + 3 * S < n4; i += 4 * S) {
        float4 P0 = p4[i];         float4 P1 = p4[i + S];
        float4 P2 = p4[i + 2 * S]; float4 P3 = p4[i + 3 * S];
        float4 W0 = w4[i];         float4 W1 = w4[i + S];
        float4 W2 = w4[i + 2 * S]; float4 W3 = w4[i + 3 * S];
        float ps[16] = {P0.x,P0.y,P0.z,P0.w, P1.x,P1.y,P1.z,P1.w,
                        P2.x,P2.y,P2.z,P2.w, P3.x,P3.y,P3.z,P3.w};
        float ws[16] = {W0.x,W0.y,W0.z,W0.w, W1.x,W1.y,W1.z,W1.w,
                        W2.x,W2.y,W2.z,W2.w, W3.x,W3.y,W3.z,W3.w};
        float os[16];
#pragma unroll
        for (int k = 0; k < 16; ++k) {
            int bin; float g;
            ghm_classify(ps[k], bin, g);
            bool ib = (ws[k] > 0.0f) && (g < EDGE_TOP);
            int idx = ib ? bin : 15;
            float wt = __int_as_float(
                __builtin_amdgcn_ds_bpermute(idx << 2, wfi));
            os[k] = wt * ps[k];
        }
        float4 O;
        O.x = os[0];  O.y = os[1];  O.z = os[2];  O.w = os[3];  o4[i]         = O;
        O.x = os[4];  O.y = os[5];  O.z = os[6];  O.w = os[7];  o4[i + S]     = O;
        O.x = os[8];  O.y = os[9];  O.z = os[10]; O.w = os[11]; o4[i + 2 * S] = O;
        O.x = os[12]; O.y = os[13]; O.z = os[14]; O.w = os[15]; o4[i + 3 * S] = O;
    }
    for (; i < n4; i += S) {
        float4 P = p4[i];
        float4 W = w4[i];
        float ps[4] = {P.x, P.y, P.z, P.w};
        float ws[4] = {W.x, W.y, W.z, W.w};
        float os[4];
#pragma unroll
        for (int k = 0; k < 4; ++k) {
            int bin; float g;
            ghm_classify(ps[k], bin, g);
            bool ib = (ws[k] > 0.0f) && (g < EDGE_TOP);
            int idx = ib ? bin : 15;
            float wt = __int_as_float(
                __builtin_amdgcn_ds_bpermute(idx << 2, wfi));
            os[k] = wt * ps[k];
        }
        float4 O;
        O.x = os[0]; O.y = os[1]; O.z = os[2]; O.w = os[3];
        o4[i] = O;
    }
    if (tid == 0) {
        for (int j = n4 << 2; j < n; ++j) {
            int bin; float g;
            ghm_classify(pred[j], bin, g);
            bool ib = (lw[j] > 0.0f) && (g < EDGE_TOP);
            int idx = ib ? bin : 15;
            float wt = __int_as_float(
                __builtin_amdgcn_ds_bpermute(idx << 2, wfi));
            out[j] = wt * pred[j];
        }
    }
}

extern "C" void kernel_launch(void* const* d_in, const int* in_sizes, int n_in,
                              void* d_out, int out_size, void* d_ws, size_t ws_size,
                              hipStream_t stream)
{
    const float* pred = (const float*)d_in[0];
    // d_in[1] = target, unused by the math
    const float* lw   = (const float*)d_in[2];
    float* out        = (float*)d_out;
    const int n       = in_sizes[0];

    unsigned int* cnt = (unsigned int*)d_ws;   // [0..9]=bin counts, [10]=valid

    // ws is poisoned 0xAA before every call — zero the counters on-stream.
    hipMemsetAsync(d_ws, 0, (BINS + 1) * sizeof(unsigned int), stream);

    ghm_hist <<<GRID, BLK, 0, stream>>>(pred, lw, cnt, n);
    ghm_apply<<<GRID, BLK, 0, stream>>>(pred, lw, cnt, out, n);
}

// Round 3
// 216.445 us; speedup vs baseline: 1.4142x; 1.4142x over previous
//
#include <hip/hip_runtime.h>
#include <cmath>

#define BINS 10
#define EDGE_TOP (1.0f + 1e-6f)
#define BLK 256

// Classify via native exp (2 instr). Near-boundary values (within 1e-4 of a
// bin edge in g*10 space, >> the ~8e-6 fast-exp error) are recomputed with
// double-precision exp so the fp32 result matches numpy's fp32 exp.
// This hazard machinery is proven: absmax 7.8e-3 vs threshold 0.385 (R1/R2).
__device__ __forceinline__ void ghm_classify_fast(float p, int& bin, bool& lt_top) {
    float ef  = __expf(-p);
    float g   = fabsf(ef - 1.0f);
    float g10 = g * 10.0f;
    int   b   = (int)g10;          // g >= 0, trunc == floor (saturating cvt)
    float fb  = (float)b;
    bool hazard = (g10 - fb < 1e-4f) || (fb + 1.0f - g10 < 1e-4f) ||
                  (fabsf(g - EDGE_TOP) < 4e-6f);
    if (hazard) {
        double ed = exp(-(double)p);
        float ef2 = (float)ed;     // ~correctly-rounded fp32 exp
        g   = fabsf(ef2 - 1.0f);
        g10 = g * 10.0f;
        b   = (int)g10;
    }
    bin    = (b < 9) ? b : 9;
    lt_top = (g < EDGE_TOP);
}

// Pass 1: per-bin counts + total valid count, and (optionally) a 4-bit code
// per element (bin, or 15 if not in-bin) packed 4-per-u16, one u16 per float4
// group, so pass 2 never re-reads lw or recomputes exp.
// Histogram lives in ONE u64 per thread: 10 x 6-bit fields (<=60 elems/thread
// enforced by the launcher, so fields can't overflow). ~8 VALU/elem vs the
// 10-compare chain (~25) of R1 and the LDS-atomic disaster of R2 (872k bank
// conflicts, ds_atomic serialization).
__global__ __launch_bounds__(BLK) void ghm_hist(
    const float* __restrict__ pred, const float* __restrict__ lw,
    unsigned int* __restrict__ cnt, unsigned short* __restrict__ codes,
    int n, int write_codes)
{
    unsigned long long h = 0ull;
    unsigned int vcnt = 0;

    const int tid = blockIdx.x * BLK + threadIdx.x;
    const int S   = gridDim.x * BLK;
    const int n4  = n >> 2;
    const float4* p4 = (const float4*)pred;
    const float4* w4 = (const float4*)lw;

    int i = tid;
    // main loop: 8 loads issued back-to-back for MLP
    for (; i + 3 * S < n4; i += 4 * S) {
        float4 P0 = p4[i];         float4 P1 = p4[i + S];
        float4 P2 = p4[i + 2 * S]; float4 P3 = p4[i + 3 * S];
        float4 W0 = w4[i];         float4 W1 = w4[i + S];
        float4 W2 = w4[i + 2 * S]; float4 W3 = w4[i + 3 * S];
        float ps[16] = {P0.x,P0.y,P0.z,P0.w, P1.x,P1.y,P1.z,P1.w,
                        P2.x,P2.y,P2.z,P2.w, P3.x,P3.y,P3.z,P3.w};
        float ws[16] = {W0.x,W0.y,W0.z,W0.w, W1.x,W1.y,W1.z,W1.w,
                        W2.x,W2.y,W2.z,W2.w, W3.x,W3.y,W3.z,W3.w};
        unsigned int code[4] = {0u, 0u, 0u, 0u};
#pragma unroll
        for (int k = 0; k < 16; ++k) {
            bool valid = ws[k] > 0.0f;
            vcnt += valid ? 1u : 0u;
            int bin; bool lt;
            ghm_classify_fast(ps[k], bin, lt);
            bool ib = valid && lt;
            h += ib ? (1ull << (bin * 6)) : 0ull;
            unsigned int idx = ib ? (unsigned int)bin : 15u;
            code[k >> 2] |= idx << ((k & 3) * 4);
        }
        if (write_codes) {
            codes[i]         = (unsigned short)code[0];
            codes[i + S]     = (unsigned short)code[1];
            codes[i + 2 * S] = (unsigned short)code[2];
            codes[i + 3 * S] = (unsigned short)code[3];
        }
    }
    for (; i < n4; i += S) {
        float4 P = p4[i];
        float4 W = w4[i];
        float ps[4] = {P.x, P.y, P.z, P.w};
        float ws[4] = {W.x, W.y, W.z, W.w};
        unsigned int code = 0u;
#pragma unroll
        for (int k = 0; k < 4; ++k) {
            bool valid = ws[k] > 0.0f;
            vcnt += valid ? 1u : 0u;
            int bin; bool lt;
            ghm_classify_fast(ps[k], bin, lt);
            bool ib = valid && lt;
            h += ib ? (1ull << (bin * 6)) : 0ull;
            unsigned int idx = ib ? (unsigned int)bin : 15u;
            code |= idx << (k * 4);
        }
        if (write_codes) codes[i] = (unsigned short)code;
    }
    // scalar tail (n % 4): counts only; apply recomputes these directly
    if (tid == 0) {
        for (int j = n4 << 2; j < n; ++j) {
            bool valid = lw[j] > 0.0f;
            vcnt += valid ? 1u : 0u;
            int bin; bool lt;
            ghm_classify_fast(pred[j], bin, lt);
            h += (valid && lt) ? (1ull << (bin * 6)) : 0ull;
        }
    }

    // unpack per-thread fields, wave shuffle-reduce, LDS combine, 11 global
    // atomics per block (the R1 ending — proven cheap)
    unsigned int vals[BINS + 1];
#pragma unroll
    for (int b = 0; b < BINS; ++b)
        vals[b] = (unsigned int)((h >> (6 * b)) & 63ull);
    vals[BINS] = vcnt;

    __shared__ unsigned int sc[BINS + 1];
    if (threadIdx.x < BINS + 1) sc[threadIdx.x] = 0u;
    __syncthreads();
#pragma unroll
    for (int b = 0; b <= BINS; ++b) {
        unsigned int v = vals[b];
#pragma unroll
        for (int off = 32; off > 0; off >>= 1)
            v += __shfl_down(v, off, 64);
        if ((threadIdx.x & 63) == 0) atomicAdd(&sc[b], v);
    }
    __syncthreads();
    if (threadIdx.x < BINS + 1) atomicAdd(&cnt[threadIdx.x], sc[threadIdx.x]);
}

// Wave-cooperative finalize (proven in R2): lane b<10 holds w[b];
// lane 15 holds 0.0 -> sentinel code 15 yields weight 0 via ds_bpermute.
__device__ __forceinline__ int ghm_wave_weights(const unsigned int* __restrict__ cnt) {
    const int lane = threadIdx.x & 63;
    unsigned int cv = cnt[lane < 10 ? lane : 10];
    float totf = fmaxf((float)__shfl((int)cv, 10, 64), 1.0f);
    unsigned long long nem = __ballot(lane < 10 && cv > 0u);
    int nne = __popcll(nem);
    float nf = fmaxf((float)nne, 1.0f);
    float wfl = 0.0f;
    if (lane < 10 && cv > 0u) {
        wfl = totf / (float)cv;      // tot / counts[b]
        if (nne > 0) wfl = wfl / nf; // / n_nonempty  (reference op order)
    }
    return __float_as_int(wfl);
}

// Pass 2 (code path): out = w[code] * pred. No lw read, no exp.
// ~4 VALU/elem: bfe, lshl, ds_bpermute, mul.
__global__ __launch_bounds__(BLK) void ghm_apply_codes(
    const float* __restrict__ pred, const float* __restrict__ lw,
    const unsigned short* __restrict__ codes,
    const unsigned int* __restrict__ cnt, float* __restrict__ out, int n)
{
    const int wfi = ghm_wave_weights(cnt);

    const int tid = blockIdx.x * BLK + threadIdx.x;
    const int S   = gridDim.x * BLK;
    const int n4  = n >> 2;
    const float4* p4 = (const float4*)pred;
    float4* o4       = (float4*)out;

    int i = tid;
    for (; i + 3 * S < n4; i += 4 * S) {
        float4 P0 = p4[i];         float4 P1 = p4[i + S];
        float4 P2 = p4[i + 2 * S]; float4 P3 = p4[i + 3 * S];
        unsigned int c0 = codes[i];         unsigned int c1 = codes[i + S];
        unsigned int c2 = codes[i + 2 * S]; unsigned int c3 = codes[i + 3 * S];
        float ps[16] = {P0.x,P0.y,P0.z,P0.w, P1.x,P1.y,P1.z,P1.w,
                        P2.x,P2.y,P2.z,P2.w, P3.x,P3.y,P3.z,P3.w};
        unsigned int cc[4] = {c0, c1, c2, c3};
        float os[16];
#pragma unroll
        for (int k = 0; k < 16; ++k) {
            unsigned int idx = (cc[k >> 2] >> ((k & 3) * 4)) & 15u;
            float wt = __int_as_float(
                __builtin_amdgcn_ds_bpermute((int)(idx << 2), wfi));
            os[k] = wt * ps[k];
        }
        float4 O;
        O.x = os[0];  O.y = os[1];  O.z = os[2];  O.w = os[3];  o4[i]         = O;
        O.x = os[4];  O.y = os[5];  O.z = os[6];  O.w = os[7];  o4[i + S]     = O;
        O.x = os[8];  O.y = os[9];  O.z = os[10]; O.w = os[11]; o4[i + 2 * S] = O;
        O.x = os[12]; O.y = os[13]; O.z = os[14]; O.w = os[15]; o4[i + 3 * S] = O;
    }
    for (; i < n4; i += S) {
        float4 P = p4[i];
        unsigned int c = codes[i];
        float ps[4] = {P.x, P.y, P.z, P.w};
        float os[4];
#pragma unroll
        for (int k = 0; k < 4; ++k) {
            unsigned int idx = (c >> (k * 4)) & 15u;
            float wt = __int_as_float(
                __builtin_amdgcn_ds_bpermute((int)(idx << 2), wfi));
            os[k] = wt * ps[k];
        }
        float4 O;
        O.x = os[0]; O.y = os[1]; O.z = os[2]; O.w = os[3];
        o4[i] = O;
    }
    // scalar tail: recompute directly (codes not written for these)
    if (tid == 0) {
        for (int j = n4 << 2; j < n; ++j) {
            int bin; bool lt;
            ghm_classify_fast(pred[j], bin, lt);
            bool ib = (lw[j] > 0.0f) && lt;
            unsigned int idx = ib ? (unsigned int)bin : 15u;
            float wt = __int_as_float(
                __builtin_amdgcn_ds_bpermute((int)(idx << 2), wfi));
            out[j] = wt * pred[j];
        }
    }
}

// Pass 2 (fallback, ws too small for codes): recompute classification.
__global__ __launch_bounds__(BLK) void ghm_apply_recompute(
    const float* __restrict__ pred, const float* __restrict__ lw,
    const unsigned int* __restrict__ cnt, float* __restrict__ out, int n)
{
    const int wfi = ghm_wave_weights(cnt);

    const int tid = blockIdx.x * BLK + threadIdx.x;
    const int S   = gridDim.x * BLK;
    const int n4  = n >> 2;
    const float4* p4 = (const float4*)pred;
    const float4* w4 = (const float4*)lw;
    float4* o4       = (float4*)out;

    for (int i = tid; i < n4; i += S) {
        float4 P = p4[i];
        float4 W = w4[i];
        float ps[4] = {P.x, P.y, P.z, P.w};
        float ws[4] = {W.x, W.y, W.z, W.w};
        float os[4];
#pragma unroll
        for (int k = 0; k < 4; ++k) {
            int bin; bool lt;
            ghm_classify_fast(ps[k], bin, lt);
            bool ib = (ws[k] > 0.0f) && lt;
            unsigned int idx = ib ? (unsigned int)bin : 15u;
            float wt = __int_as_float(
                __builtin_amdgcn_ds_bpermute((int)(idx << 2), wfi));
            os[k] = wt * ps[k];
        }
        float4 O;
        O.x = os[0]; O.y = os[1]; O.z = os[2]; O.w = os[3];
        o4[i] = O;
    }
    if (tid == 0) {
        for (int j = n4 << 2; j < n; ++j) {
            int bin; bool lt;
            ghm_classify_fast(pred[j], bin, lt);
            bool ib = (lw[j] > 0.0f) && lt;
            unsigned int idx = ib ? (unsigned int)bin : 15u;
            float wt = __int_as_float(
                __builtin_amdgcn_ds_bpermute((int)(idx << 2), wfi));
            out[j] = wt * pred[j];
        }
    }
}

extern "C" void kernel_launch(void* const* d_in, const int* in_sizes, int n_in,
                              void* d_out, int out_size, void* d_ws, size_t ws_size,
                              hipStream_t stream)
{
    const float* pred = (const float*)d_in[0];
    // d_in[1] = target, unused by the math
    const float* lw   = (const float*)d_in[2];
    float* out        = (float*)d_out;
    const int n       = in_sizes[0];
    const int n4      = n >> 2;

    unsigned int* cnt     = (unsigned int*)d_ws;           // [0..9]=bins, [10]=valid
    unsigned short* codes = (unsigned short*)((char*)d_ws + 64);
    const size_t need     = 64 + (size_t)n4 * sizeof(unsigned short);
    const int use_codes   = (ws_size >= need) ? 1 : 0;

    // ws is poisoned 0xAA before every call — zero the counters on-stream.
    hipMemsetAsync(d_ws, 0, (BINS + 1) * sizeof(unsigned int), stream);

    // G=2000: n4=4.096M divides exactly into 8 float4s (32 elems) per thread.
    // Keep <=15 float4s (60 elems) per thread so 6-bit packed fields can't
    // overflow (max 60+3 tail = 63).
    int G = 2000;
    while ((long long)(n4 + (long long)G * BLK - 1) / ((long long)G * BLK) > 15)
        G *= 2;

    ghm_hist<<<G, BLK, 0, stream>>>(pred, lw, cnt, codes, n, use_codes);
    if (use_codes)
        ghm_apply_codes<<<G, BLK, 0, stream>>>(pred, lw, codes, cnt, out, n);
    else
        ghm_apply_recompute<<<G, BLK, 0, stream>>>(pred, lw, cnt, out, n);
}